// Round 1
// baseline (96.206 us; speedup 1.0000x reference)
//
#include <hip/hip_runtime.h>

#define D_MODEL 128
#define NBANDS 12
#define NHEADS 2
#define HDIM 64
#define NCONSTS 364   // a[2] e[2] u[24] v[24] g[24] w[288]

// ---------------------------------------------------------------------------
// Kernel 1: project the 39 column vectors through Wq/Wk/Wv.
//   inter[(m*13 + c)*128 + t], m in {0=q,1=k,2=v}
//   c==0  -> M @ w_embed                    (no bias)
//   c>=1  -> M @ (b_embed + band_pos[c-1]) + bias   (the per-band constant)
// ---------------------------------------------------------------------------
__global__ void spectral_inter_kernel(
    const float* __restrict__ w_embed, const float* __restrict__ b_embed,
    const float* __restrict__ band_pos,
    const float* __restrict__ Wq, const float* __restrict__ bq,
    const float* __restrict__ Wk, const float* __restrict__ bk,
    const float* __restrict__ Wv, const float* __restrict__ bv,
    float* __restrict__ inter)
{
    const int m = blockIdx.x / 13;
    const int c = blockIdx.x % 13;
    const int t = threadIdx.x;  // output row 0..127
    const float* M    = (m == 0) ? Wq : (m == 1) ? Wk : Wv;
    const float* bias = (m == 0) ? bq : (m == 1) ? bk : bv;
    const float* row  = M + t * D_MODEL;
    float s = 0.f;
    if (c == 0) {
        #pragma unroll 8
        for (int j = 0; j < D_MODEL; ++j) s = fmaf(row[j], w_embed[j], s);
    } else {
        const float* bpr = band_pos + (c - 1) * D_MODEL;
        #pragma unroll 8
        for (int j = 0; j < D_MODEL; ++j) s = fmaf(row[j], b_embed[j] + bpr[j], s);
        s += bias[t];
    }
    inter[(m * 13 + c) * D_MODEL + t] = s;
}

// ---------------------------------------------------------------------------
// Kernel 2: each block rebuilds the 364 closed-form constants into LDS
// (cheap: 364 64-length dots from L2-hot intermediates), then one thread per
// token evaluates the collapsed attention on its 12 band scalars.
// ---------------------------------------------------------------------------
__global__ __launch_bounds__(256) void spectral_main_kernel(
    const float* __restrict__ x, const float* __restrict__ Wo,
    const float* __restrict__ bo, const float* __restrict__ inter,
    float* __restrict__ out, int n_tokens)
{
    __shared__ float sc[NCONSTS];
    const int t = threadIdx.x;
    const float* qv = inter;                  // [13][128]: qw, qc[0..11]
    const float* kv = inter + 13 * D_MODEL;   // kw, kc[0..11]
    const float* vv = inter + 26 * D_MODEL;   // vw, vc[0..11]

    for (int idx = t; idx < NCONSTS; idx += 256) {
        float s = 0.f;
        if (idx < 2) {                                  // a_h = scale * qw.kw|h
            int h = idx;
            for (int d = 0; d < HDIM; ++d) s = fmaf(qv[h*HDIM+d], kv[h*HDIM+d], s);
            s *= 0.125f;
        } else if (idx < 4) {                           // e_h = vw.Wo|h
            int h = idx - 2;
            for (int d = 0; d < HDIM; ++d) s = fmaf(vv[h*HDIM+d], Wo[h*HDIM+d], s);
        } else if (idx < 28) {                          // u_h[k] = scale * qw.kc[k]|h
            int i = idx - 4, h = i / NBANDS, k = i % NBANDS;
            const float* kc = kv + (1 + k) * D_MODEL;
            for (int d = 0; d < HDIM; ++d) s = fmaf(qv[h*HDIM+d], kc[h*HDIM+d], s);
            s *= 0.125f;
        } else if (idx < 52) {                          // v_h[q] = scale * qc[q].kw|h
            int i = idx - 28, h = i / NBANDS, q = i % NBANDS;
            const float* qc = qv + (1 + q) * D_MODEL;
            for (int d = 0; d < HDIM; ++d) s = fmaf(qc[h*HDIM+d], kv[h*HDIM+d], s);
            s *= 0.125f;
        } else if (idx < 76) {                          // g_h[k] = vc[k].Wo|h
            int i = idx - 52, h = i / NBANDS, k = i % NBANDS;
            const float* vc = vv + (1 + k) * D_MODEL;
            for (int d = 0; d < HDIM; ++d) s = fmaf(vc[h*HDIM+d], Wo[h*HDIM+d], s);
        } else {                                        // w_h[q][k] = scale * qc[q].kc[k]|h
            int i = idx - 76, h = i / (NBANDS*NBANDS);
            int q = (i / NBANDS) % NBANDS, k = i % NBANDS;
            const float* qc = qv + (1 + q) * D_MODEL;
            const float* kc = kv + (1 + k) * D_MODEL;
            for (int d = 0; d < HDIM; ++d) s = fmaf(qc[h*HDIM+d], kc[h*HDIM+d], s);
            s *= 0.125f;
        }
        sc[idx] = s;
    }
    __syncthreads();

    const int n = blockIdx.x * 256 + t;
    if (n >= n_tokens) return;

    // 12 contiguous floats per token; n*12 floats = n*48 B, always 16B-aligned
    const float4* xin = reinterpret_cast<const float4*>(x + (size_t)n * NBANDS);
    float4 p0 = xin[0], p1 = xin[1], p2 = xin[2];
    float xb[NBANDS] = {p0.x,p0.y,p0.z,p0.w, p1.x,p1.y,p1.z,p1.w, p2.x,p2.y,p2.z,p2.w};

    float acc[NBANDS];
    const float bo_v = bo[0];
    #pragma unroll
    for (int q = 0; q < NBANDS; ++q) acc[q] = bo_v;

    #pragma unroll
    for (int h = 0; h < NHEADS; ++h) {
        const float a = sc[h];
        const float e = sc[2 + h];
        const float* u = &sc[4  + h * NBANDS];
        const float* v = &sc[28 + h * NBANDS];
        const float* g = &sc[52 + h * NBANDS];
        const float* w = &sc[76 + h * NBANDS * NBANDS];
        for (int q = 0; q < NBANDS; ++q) {
            const float xq   = xb[q];
            const float coef = fmaf(a, xq, v[q]);   // (a*xq + v[q])
            const float* wq  = w + q * NBANDS;
            float s[NBANDS];
            float m = -1e30f;
            #pragma unroll
            for (int k = 0; k < NBANDS; ++k) {
                // S = (a*xq + v[q])*xk + (u[k]*xq + w[q][k]); scale pre-folded
                float sv = fmaf(coef, xb[k], fmaf(u[k], xq, wq[k]));
                s[k] = sv;
                m = fmaxf(m, sv);
            }
            float den = 0.f, num = 0.f;
            #pragma unroll
            for (int k = 0; k < NBANDS; ++k) {
                float p = __expf(s[k] - m);
                den += p;
                num  = fmaf(p, fmaf(e, xb[k], g[k]), num);
            }
            acc[q] = fmaf(num, __builtin_amdgcn_rcpf(den), acc[q]);
        }
    }

    float4 o0 = make_float4(p0.x + acc[0], p0.y + acc[1], p0.z + acc[2],  p0.w + acc[3]);
    float4 o1 = make_float4(p1.x + acc[4], p1.y + acc[5], p1.z + acc[6],  p1.w + acc[7]);
    float4 o2 = make_float4(p2.x + acc[8], p2.y + acc[9], p2.z + acc[10], p2.w + acc[11]);
    float4* op = reinterpret_cast<float4*>(out + (size_t)n * NBANDS);
    op[0] = o0; op[1] = o1; op[2] = o2;
}

extern "C" void kernel_launch(void* const* d_in, const int* in_sizes, int n_in,
                              void* d_out, int out_size, void* d_ws, size_t ws_size,
                              hipStream_t stream)
{
    const float* x  = (const float*)d_in[0];
    const float* we = (const float*)d_in[1];
    const float* be = (const float*)d_in[2];
    const float* bp = (const float*)d_in[3];
    const float* Wq = (const float*)d_in[4];
    const float* bq = (const float*)d_in[5];
    const float* Wk = (const float*)d_in[6];
    const float* bk = (const float*)d_in[7];
    const float* Wv = (const float*)d_in[8];
    const float* bv = (const float*)d_in[9];
    const float* Wo = (const float*)d_in[10];
    const float* bo = (const float*)d_in[11];
    float* out   = (float*)d_out;
    float* inter = (float*)d_ws;   // 39*128 floats = 19968 B of scratch

    const int n_tokens = in_sizes[0] / NBANDS;

    hipLaunchKernelGGL(spectral_inter_kernel, dim3(39), dim3(128), 0, stream,
                       we, be, bp, Wq, bq, Wk, bk, Wv, bv, inter);
    hipLaunchKernelGGL(spectral_main_kernel,
                       dim3((n_tokens + 255) / 256), dim3(256), 0, stream,
                       x, Wo, bo, inter, out, n_tokens);
}

// Round 2
// 96.093 us; speedup vs baseline: 1.0012x; 1.0012x over previous
//
#include <hip/hip_runtime.h>

#define D_MODEL 128
#define NBANDS 12
#define NHEADS 2
#define HDIM 64
#define NCONSTS 364   // a[2] e[2] u[24] v[24] g[24] w[288]
#define NINTER (39 * D_MODEL)

// ---------------------------------------------------------------------------
// Kernel A: project the 39 column vectors through Wq/Wk/Wv.
//   inter[(m*13 + c)*128 + t], m in {0=q,1=k,2=v}
//   c==0  -> M @ w_embed                    (no bias)
//   c>=1  -> M @ (b_embed + band_pos[c-1]) + bias
// ---------------------------------------------------------------------------
__global__ void spectral_inter_kernel(
    const float* __restrict__ w_embed, const float* __restrict__ b_embed,
    const float* __restrict__ band_pos,
    const float* __restrict__ Wq, const float* __restrict__ bq,
    const float* __restrict__ Wk, const float* __restrict__ bk,
    const float* __restrict__ Wv, const float* __restrict__ bv,
    float* __restrict__ inter)
{
    const int m = blockIdx.x / 13;
    const int c = blockIdx.x % 13;
    const int t = threadIdx.x;  // output row 0..127
    const float* M    = (m == 0) ? Wq : (m == 1) ? Wk : Wv;
    const float* bias = (m == 0) ? bq : (m == 1) ? bk : bv;
    const float* row  = M + t * D_MODEL;
    float s = 0.f;
    if (c == 0) {
        #pragma unroll 8
        for (int j = 0; j < D_MODEL; ++j) s = fmaf(row[j], w_embed[j], s);
    } else {
        const float* bpr = band_pos + (c - 1) * D_MODEL;
        #pragma unroll 8
        for (int j = 0; j < D_MODEL; ++j) s = fmaf(row[j], b_embed[j] + bpr[j], s);
        s += bias[t];
    }
    inter[(m * 13 + c) * D_MODEL + t] = s;
}

// ---------------------------------------------------------------------------
// Kernel B: one block derives the 364 closed-form constants.
//   consts layout: a[2] e[2] u[2][12] v[2][12] g[2][12] w[2][12][12]
// ---------------------------------------------------------------------------
__global__ __launch_bounds__(384) void spectral_consts_kernel(
    const float* __restrict__ inter, const float* __restrict__ Wo,
    float* __restrict__ consts)
{
    __shared__ float si[NINTER];     // 4992 floats = 19.5 KB
    __shared__ float swo[D_MODEL];
    const int t = threadIdx.x;
    for (int i = t; i < NINTER; i += 384) si[i] = inter[i];
    for (int i = t; i < D_MODEL; i += 384) swo[i] = Wo[i];
    __syncthreads();

    const int idx = t;
    if (idx >= NCONSTS) return;
    const float* qv = si;                  // [13][128]: qw, qc[0..11]
    const float* kv = si + 13 * D_MODEL;   // kw, kc[0..11]
    const float* vv = si + 26 * D_MODEL;   // vw, vc[0..11]

    float s = 0.f;
    if (idx < 2) {                                  // a_h = scale * qw.kw|h
        int h = idx;
        #pragma unroll 8
        for (int d = 0; d < HDIM; ++d) s = fmaf(qv[h*HDIM+d], kv[h*HDIM+d], s);
        s *= 0.125f;
    } else if (idx < 4) {                           // e_h = vw.Wo|h
        int h = idx - 2;
        #pragma unroll 8
        for (int d = 0; d < HDIM; ++d) s = fmaf(vv[h*HDIM+d], swo[h*HDIM+d], s);
    } else if (idx < 28) {                          // u_h[k] = scale * qw.kc[k]|h
        int i = idx - 4, h = i / NBANDS, k = i % NBANDS;
        const float* kc = kv + (1 + k) * D_MODEL;
        #pragma unroll 8
        for (int d = 0; d < HDIM; ++d) s = fmaf(qv[h*HDIM+d], kc[h*HDIM+d], s);
        s *= 0.125f;
    } else if (idx < 52) {                          // v_h[q] = scale * qc[q].kw|h
        int i = idx - 28, h = i / NBANDS, q = i % NBANDS;
        const float* qc = qv + (1 + q) * D_MODEL;
        #pragma unroll 8
        for (int d = 0; d < HDIM; ++d) s = fmaf(qc[h*HDIM+d], kv[h*HDIM+d], s);
        s *= 0.125f;
    } else if (idx < 76) {                          // g_h[k] = vc[k].Wo|h
        int i = idx - 52, h = i / NBANDS, k = i % NBANDS;
        const float* vc = vv + (1 + k) * D_MODEL;
        #pragma unroll 8
        for (int d = 0; d < HDIM; ++d) s = fmaf(vc[h*HDIM+d], swo[h*HDIM+d], s);
    } else {                                        // w_h[q][k] = scale * qc[q].kc[k]|h
        int i = idx - 76, h = i / (NBANDS*NBANDS);
        int q = (i / NBANDS) % NBANDS, k = i % NBANDS;
        const float* qc = qv + (1 + q) * D_MODEL;
        const float* kc = kv + (1 + k) * D_MODEL;
        #pragma unroll 8
        for (int d = 0; d < HDIM; ++d) s = fmaf(qc[h*HDIM+d], kc[h*HDIM+d], s);
        s *= 0.125f;
    }
    consts[idx] = s;
}

// ---------------------------------------------------------------------------
// Kernel C: one thread per (token, q). All inner loops fully unrolled — no
// dynamically-indexed register arrays (the R1 scratch-spill bug). xq is read
// directly as x[tid]; LDS const reads are broadcast or <=2-way bank aliased.
// ---------------------------------------------------------------------------
__global__ __launch_bounds__(256) void spectral_main_kernel(
    const float* __restrict__ x, const float* __restrict__ bo,
    const float* __restrict__ consts, float* __restrict__ out, int n_total)
{
    __shared__ float sc[NCONSTS];
    const int t = threadIdx.x;
    for (int i = t; i < NCONSTS; i += 256) sc[i] = consts[i];
    __syncthreads();

    const int tid = blockIdx.x * 256 + t;
    if (tid >= n_total) return;

    const unsigned n = (unsigned)tid / 12u;   // magic-mul div
    const int q = tid - (int)n * 12;

    const float4* xin = reinterpret_cast<const float4*>(x + (size_t)n * NBANDS);
    float4 p0 = xin[0], p1 = xin[1], p2 = xin[2];
    float xb[NBANDS] = {p0.x,p0.y,p0.z,p0.w, p1.x,p1.y,p1.z,p1.w, p2.x,p2.y,p2.z,p2.w};
    const float xq = x[tid];   // == xb[q] without dynamic reg indexing

    float acc = bo[0];
    #pragma unroll
    for (int h = 0; h < NHEADS; ++h) {
        const float a = sc[h];
        const float e = sc[2 + h];
        const float* u  = &sc[4  + h * NBANDS];
        const float vq  = sc[28 + h * NBANDS + q];
        const float* g  = &sc[52 + h * NBANDS];
        const float* wq = &sc[76 + h * NBANDS * NBANDS + q * NBANDS];
        const float coef = fmaf(a, xq, vq);
        float s[NBANDS];
        float m = -1e30f;
        #pragma unroll
        for (int k = 0; k < NBANDS; ++k) {
            float sv = fmaf(coef, xb[k], fmaf(u[k], xq, wq[k]));
            s[k] = sv;
            m = fmaxf(m, sv);
        }
        float den = 0.f, num = 0.f;
        #pragma unroll
        for (int k = 0; k < NBANDS; ++k) {
            float p = __expf(s[k] - m);
            den += p;
            num  = fmaf(p, fmaf(e, xb[k], g[k]), num);
        }
        acc = fmaf(num, __builtin_amdgcn_rcpf(den), acc);
    }

    out[tid] = xq + acc;
}

extern "C" void kernel_launch(void* const* d_in, const int* in_sizes, int n_in,
                              void* d_out, int out_size, void* d_ws, size_t ws_size,
                              hipStream_t stream)
{
    const float* x  = (const float*)d_in[0];
    const float* we = (const float*)d_in[1];
    const float* be = (const float*)d_in[2];
    const float* bp = (const float*)d_in[3];
    const float* Wq = (const float*)d_in[4];
    const float* bq = (const float*)d_in[5];
    const float* Wk = (const float*)d_in[6];
    const float* bk = (const float*)d_in[7];
    const float* Wv = (const float*)d_in[8];
    const float* bv = (const float*)d_in[9];
    const float* Wo = (const float*)d_in[10];
    const float* bo = (const float*)d_in[11];
    float* out    = (float*)d_out;
    float* inter  = (float*)d_ws;              // 4992 floats
    float* consts = (float*)d_ws + NINTER;     // 364 floats

    const int n_total = in_sizes[0];           // tokens * 12

    hipLaunchKernelGGL(spectral_inter_kernel, dim3(39), dim3(128), 0, stream,
                       we, be, bp, Wq, bq, Wk, bk, Wv, bv, inter);
    hipLaunchKernelGGL(spectral_consts_kernel, dim3(1), dim3(384), 0, stream,
                       inter, Wo, consts);
    hipLaunchKernelGGL(spectral_main_kernel,
                       dim3((n_total + 255) / 256), dim3(256), 0, stream,
                       x, bo, consts, out, n_total);
}